// Round 4
// baseline (261.911 us; speedup 1.0000x reference)
//
#include <hip/hip_runtime.h>
#include <hip/hip_bf16.h>
#include <stddef.h>

// Correlation cost volume via bf16 MFMA band-matmul.
// out[b, di*9+dj, h, w] = (1/256) * sum_c x1[b,c,h,w] * x2[b,c,h+di-4,w+dj-4]
// B=4, C=256, H=96, W=192.
//
// R4: (1) lgkm-only barrier so prefetched global loads stay in flight across
// the per-chunk barrier (full __syncthreads drains vmcnt(0) -> R3's pipeline
// was defeated); (2) k-group-of-4 LDS layout: b64 stores <=3-way on banks
// (was ~6-way b32 -> 81k conflict cyc/CU), b64 frag reads conflict-free;
// (3) 2 blocks/CU (launch_bounds(512,4), double-buffered LDS, 1 barrier/chunk)
// + XCD-contiguous block swizzle.

#define NB 4
#define NC 256
#define HH 96
#define WW 192
#define CHW (HH * WW)      // 18432
#define TW 16
#define TH 8
#define KC 32
#define NROWS 16
#define KS4 100            // shorts per k-group slot row (24 n * 4 + 4 pad)
#define RS4 808            // shorts per LDS row (8 kg * 100 + 8) -> +20 banks/row
#define BUFSH (NROWS * RS4)   // 12928 shorts = 25856 B per buffer

typedef __attribute__((ext_vector_type(8))) short bf16x8;
typedef __attribute__((ext_vector_type(4))) float f32x4;

union Frag { unsigned long long u[2]; unsigned int w[4]; bf16x8 v; };

__device__ __forceinline__ unsigned int pk2(float a, float b) {
    __hip_bfloat162 t = __float22bfloat162_rn(make_float2(a, b));
    union { __hip_bfloat162 h; unsigned int u; } c; c.h = t; return c.u;
}

// barrier that drains LDS ops only: prefetched global->VGPR loads (private)
// legally stay in flight across it.
__device__ __forceinline__ void lds_barrier() {
    __asm__ volatile("s_waitcnt lgkmcnt(0)\n\ts_barrier" ::: "memory");
}

__global__ __launch_bounds__(512, 4) void corr_mfma(
    const float* __restrict__ x1, const float* __restrict__ x2,
    float* __restrict__ out)
{
    __shared__ union {
        unsigned short xb[2][BUFSH];       // 51712 B double-buffered x2 tile
        float band[TH][9][9][18];          // 46656 B epilogue staging
    } lds;

    const int tid  = threadIdx.x;
    const int wv   = tid >> 6;        // wave 0..7 -> h row
    const int lane = tid & 63;
    const int col  = lane & 15;
    const int q    = lane >> 4;

    // XCD-contiguous swizzle: XCD k gets 72 consecutive tiles (12x6 slab of b0..)
    const int nid = (blockIdx.x & 7) * 72 + (blockIdx.x >> 3);
    const int w0  = (nid % 12) * TW;
    const int h0  = ((nid / 12) % 12) * TH;
    const int b   = nid / 144;
    const int h   = h0 + wv;

    // 3 staging tasks/thread: task t -> (w2 = t%12, row = (t/12)&15, cg = t/192)
    // each task: 4 channels (cg*4..+3) x 2 w at one x2 row -> 4 float2 loads,
    // 2 ds_write_b64.
    int  toff[3]; int tlds[3]; bool tok[3];
#pragma unroll
    for (int k = 0; k < 3; ++k) {
        int t   = tid + k * 512;
        int w2  = t % 12;
        int row = (t / 12) & 15;
        int cg  = t / 192;
        int gh  = h0 - 4 + row;
        int gw  = w0 - 4 + w2 * 2;
        tok[k]  = (gh >= 0) & (gh < HH) & (gw >= 0) & (gw < WW - 1);
        toff[k] = ((b * NC + cg * 4) * HH + gh) * WW + gw;
        tlds[k] = row * RS4 + cg * KS4 + w2 * 8;
    }
    const int x1off = ((b * NC + q * 8) * HH + h) * WW + w0 + col;

    f32x4 acc[9][2];
#pragma unroll
    for (int di = 0; di < 9; ++di) {
        acc[di][0] = (f32x4)0.0f;
        acc[di][1] = (f32x4)0.0f;
    }

    float pf[3][4][2];   // [task][chan][w] prefetched x2
    float pa[8];         // prefetched x1

#define STAGE_LOAD(KCV)                                                        \
    _Pragma("unroll")                                                          \
    for (int k = 0; k < 3; ++k) {                                              \
        int o = toff[k] + (KCV) * CHW;                                         \
        _Pragma("unroll")                                                      \
        for (int i = 0; i < 4; ++i) {                                          \
            float2 v = make_float2(0.f, 0.f);                                  \
            if (tok[k]) v = *(const float2*)&x2[o + i * CHW];                  \
            pf[k][i][0] = v.x; pf[k][i][1] = v.y;                              \
        }                                                                      \
    }

#define X1_LOAD(KCV)                                                           \
    _Pragma("unroll")                                                          \
    for (int j = 0; j < 8; ++j) pa[j] = x1[x1off + ((KCV) + j) * CHW];

    STAGE_LOAD(0)
    X1_LOAD(0)

    for (int ci = 0; ci < 8; ++ci) {
        unsigned short* xb = lds.xb[ci & 1];

        // ---- convert + store staged x2 (waits only on pf's own loads)
#pragma unroll
        for (int k = 0; k < 3; ++k) {
#pragma unroll
            for (int p = 0; p < 2; ++p) {
                uint2 u = make_uint2(pk2(pf[k][0][p], pf[k][1][p]),
                                     pk2(pf[k][2][p], pf[k][3][p]));
                *(uint2*)&xb[tlds[k] + p * 4] = u;   // ds_write_b64
            }
        }
        // ---- pack A fragment (consumes pa)
        Frag fa;
#pragma unroll
        for (int jj = 0; jj < 4; ++jj) fa.w[jj] = pk2(pa[2 * jj], pa[2 * jj + 1]);

        // ---- issue next chunk's loads; they stay in flight across the barrier
        if (ci < 7) { STAGE_LOAD((ci + 1) * KC) X1_LOAD((ci + 1) * KC) }

        lds_barrier();   // lgkm-only: orders ds_writes, does NOT drain vmcnt

        // ---- 9 displacements x 2 n-halves; frags = 2x ds_read_b64 each
#pragma unroll
        for (int di = 0; di < 9; ++di) {
            int rb = (wv + di) * RS4 + q * (2 * KS4) + col * 4;
            Frag b0, b1;
            b0.u[0] = *(const unsigned long long*)&xb[rb];
            b0.u[1] = *(const unsigned long long*)&xb[rb + KS4];
            b1.u[0] = *(const unsigned long long*)&xb[rb + 64];
            b1.u[1] = *(const unsigned long long*)&xb[rb + KS4 + 64];
            acc[di][0] = __builtin_amdgcn_mfma_f32_16x16x32_bf16(fa.v, b0.v, acc[di][0], 0, 0, 0);
            acc[di][1] = __builtin_amdgcn_mfma_f32_16x16x32_bf16(fa.v, b1.v, acc[di][1], 0, 0, 0);
        }
        // no trailing barrier: next iter writes the OTHER buffer; a buffer is
        // rewritten only after the barrier of the following chunk, by which
        // point every wave's reads of it have completed (lgkmcnt(0) at barrier).
    }

    __syncthreads();   // all frag reads done before band overwrites xb

    // ---- band extraction: P[m, m+dj] -> band[wv][di][dj][m]
    // D layout: col = lane&15 (=n), row m = q*4 + reg.
#pragma unroll
    for (int di = 0; di < 9; ++di)
#pragma unroll
        for (int half = 0; half < 2; ++half)
#pragma unroll
            for (int r = 0; r < 4; ++r) {
                int m  = q * 4 + r;
                int dj = half * 16 + col - m;
                if (dj >= 0 && dj < 9)
                    lds.band[wv][di][dj][m] = acc[di][half][r];
            }
    __syncthreads();

    // ---- coalesced write-out: 81 channels x 16 w per (b, h)
    const float scale = 1.0f / 256.0f;
#pragma unroll
    for (int it = 0; it < 21; ++it) {
        int combo = it * 4 + q;           // (di*9+dj)
        if (combo < 81) {
            float v = lds.band[wv][combo / 9][combo % 9][col];
            out[((size_t)((b * 81 + combo) * HH + h)) * WW + w0 + col] = v * scale;
        }
    }
}

extern "C" void kernel_launch(void* const* d_in, const int* in_sizes, int n_in,
                              void* d_out, int out_size, void* d_ws, size_t ws_size,
                              hipStream_t stream) {
    const float* x1 = (const float*)d_in[0];
    const float* x2 = (const float*)d_in[1];
    float* out = (float*)d_out;

    corr_mfma<<<dim3(576), dim3(512), 0, stream>>>(x1, x2, out);
}

// Round 5
// 255.288 us; speedup vs baseline: 1.0259x; 1.0259x over previous
//
#include <hip/hip_runtime.h>
#include <hip/hip_bf16.h>
#include <stddef.h>

// Correlation cost volume via bf16 MFMA band-matmul.
// out[b, di*9+dj, h, w] = (1/256) * sum_c x1[b,c,h,w] * x2[b,c,h+di-4,w+dj-4]
// B=4, C=256, H=96, W=192.
//
// R5 = best-of-R3/R4 recombination. Cross-round invariant: every variant
// saturates ~2.2-2.8 TB/s of request-side memory traffic (all pipes <12%
// busy) -> request-throughput-bound. So: float4 staging (R3's, half the
// request count of R4's float2) + conflict-free k-group-of-4 b64 LDS layout
// (R4's, 2.07e7 -> 2.2e6 conflict cycles) + lgkm-only barriers so prefetched
// loads stay in flight + unswizzled grid + (512,1) single-block residency
// (R3's 1-block was faster than R4's 2-block).

#define NB 4
#define NC 256
#define HH 96
#define WW 192
#define CHW (HH * WW)      // 18432
#define TW 16
#define TH 8
#define KC 32
#define NROWS 16
// LDS layout (shorts): [row][kg=k/4][n][k%4]; slot = 4 shorts = b64.
#define KS4 100            // kg stride: 24 n * 4 + 4 pad  (200 B = 50 banks)
#define RS4 808            // row stride: 8*100 + 8        (1616 B, +20 banks/row)
#define XBI4(row, kg, n) ((row) * RS4 + (kg) * KS4 + (n) * 4)

typedef __attribute__((ext_vector_type(8))) short bf16x8;
typedef __attribute__((ext_vector_type(4))) float f32x4;

union Frag { unsigned long long u[2]; unsigned int w[4]; bf16x8 v; };

__device__ __forceinline__ unsigned int pk2(float a, float b) {
    __hip_bfloat162 t = __float22bfloat162_rn(make_float2(a, b));
    union { __hip_bfloat162 h; unsigned int u; } c; c.h = t; return c.u;
}

// Barrier draining LDS ops only: global->VGPR prefetch loads (private
// destinations) legally stay in flight across it.
__device__ __forceinline__ void lds_barrier() {
    __asm__ volatile("s_waitcnt lgkmcnt(0)\n\ts_barrier" ::: "memory");
}

__global__ __launch_bounds__(512, 1) void corr_mfma(
    const float* __restrict__ x1, const float* __restrict__ x2,
    float* __restrict__ out)
{
    __shared__ union {
        unsigned short xb[NROWS * RS4];    // 25856 B: x2 bf16 tile
        float band[TH][9][9][18];          // 46656 B: epilogue staging
    } lds;

    const int tid  = threadIdx.x;
    const int wv   = tid >> 6;        // wave 0..7 -> h row
    const int lane = tid & 63;
    const int col  = lane & 15;
    const int q    = lane >> 4;
    const int w0   = blockIdx.x * TW;
    const int h0   = blockIdx.y * TH;
    const int b    = blockIdx.z;
    const int h    = h0 + wv;

    // Staging: 768 float4-tasks; task t = (seg = t%6, row = (t/6)&15, cg = t/96)
    // loads 4 channels (cg*4..+3) x 4 w (gw = w0-4+seg*4). Threads < 256 take a
    // second task (t = tid + 512). 16B-aligned float4 never straddles the
    // zero-pad boundary (gw is 4-aligned, W = 192).
    const int ntask = (tid < 256) ? 2 : 1;
    int toff[2]; int tlds[2]; bool tok[2];
#pragma unroll
    for (int k = 0; k < 2; ++k) {
        int t   = (k == 0) ? tid : (tid + 512);
        int seg = t % 6;
        int row = (t / 6) & 15;
        int cg  = t / 96;               // 0..7 = kg
        int gh  = h0 - 4 + row;
        int gw  = w0 - 4 + seg * 4;
        tok[k]  = (gh >= 0) & (gh < HH) & (gw >= 0) & (gw + 3 < WW);
        toff[k] = ((b * NC + cg * 4) * HH + gh) * WW + gw;
        tlds[k] = XBI4(row, cg, seg * 4);
    }
    const int x1off = ((b * NC + q * 8) * HH + h) * WW + w0 + col;

    f32x4 acc[9][2];
#pragma unroll
    for (int di = 0; di < 9; ++di) {
        acc[di][0] = (f32x4)0.0f;
        acc[di][1] = (f32x4)0.0f;
    }

    float pf[2][4][4];   // [task][chan][w] prefetched x2
    float pa[8];         // prefetched x1

#define STAGE_LOAD(KCV)                                                        \
    _Pragma("unroll")                                                          \
    for (int k = 0; k < 2; ++k) {                                              \
        if (k < ntask) {                                                       \
            int o = toff[k] + (KCV) * CHW;                                     \
            _Pragma("unroll")                                                  \
            for (int i = 0; i < 4; ++i) {                                      \
                float4 v = make_float4(0.f, 0.f, 0.f, 0.f);                    \
                if (tok[k]) v = *(const float4*)&x2[o + i * CHW];              \
                pf[k][i][0] = v.x; pf[k][i][1] = v.y;                          \
                pf[k][i][2] = v.z; pf[k][i][3] = v.w;                          \
            }                                                                  \
        }                                                                      \
    }

#define X1_LOAD(KCV)                                                           \
    _Pragma("unroll")                                                          \
    for (int j = 0; j < 8; ++j) pa[j] = x1[x1off + ((KCV) + j) * CHW];

    STAGE_LOAD(0)
    X1_LOAD(0)

    for (int ci = 0; ci < 8; ++ci) {
        // ---- convert + store staged x2 (vmcnt wait on this chunk's pf only)
#pragma unroll
        for (int k = 0; k < 2; ++k) {
            if (k < ntask) {
#pragma unroll
                for (int p = 0; p < 4; ++p) {
                    uint2 u = make_uint2(pk2(pf[k][0][p], pf[k][1][p]),
                                         pk2(pf[k][2][p], pf[k][3][p]));
                    *(uint2*)&lds.xb[tlds[k] + p * 4] = u;   // ds_write_b64
                }
            }
        }
        // ---- pack A fragment (consumes pa)
        Frag fa;
#pragma unroll
        for (int jj = 0; jj < 4; ++jj) fa.w[jj] = pk2(pa[2 * jj], pa[2 * jj + 1]);

        lds_barrier();   // stores visible; does NOT drain vmcnt

        // ---- issue next chunk's loads: in flight across MFMA phase + barrier
        if (ci < 7) { STAGE_LOAD((ci + 1) * KC) X1_LOAD((ci + 1) * KC) }

        // ---- 9 displacements x 2 n-halves; frags = 2x conflict-free b64 each
#pragma unroll
        for (int di = 0; di < 9; ++di) {
            int rb = XBI4(wv + di, 2 * q, col);
            Frag b0, b1;
            b0.u[0] = *(const unsigned long long*)&lds.xb[rb];          // k0..3
            b0.u[1] = *(const unsigned long long*)&lds.xb[rb + KS4];    // k4..7
            b1.u[0] = *(const unsigned long long*)&lds.xb[rb + 64];     // n+16
            b1.u[1] = *(const unsigned long long*)&lds.xb[rb + KS4 + 64];
            acc[di][0] = __builtin_amdgcn_mfma_f32_16x16x32_bf16(fa.v, b0.v, acc[di][0], 0, 0, 0);
            acc[di][1] = __builtin_amdgcn_mfma_f32_16x16x32_bf16(fa.v, b1.v, acc[di][1], 0, 0, 0);
        }

        lds_barrier();   // this wave's reads drained (lgkm) + all waves passed
                         // -> safe to overwrite buffer next iteration
    }

    // ---- band extraction: P[m, m+dj] -> band[wv][di][dj][m]
    // D layout: col = lane&15 (=n), row m = q*4 + reg.
#pragma unroll
    for (int di = 0; di < 9; ++di)
#pragma unroll
        for (int half = 0; half < 2; ++half)
#pragma unroll
            for (int r = 0; r < 4; ++r) {
                int m  = q * 4 + r;
                int dj = half * 16 + col - m;
                if (dj >= 0 && dj < 9)
                    lds.band[wv][di][dj][m] = acc[di][half][r];
            }
    lds_barrier();

    // ---- coalesced write-out: 81 channels x 16 w per (b, h)
    const float scale = 1.0f / 256.0f;
#pragma unroll
    for (int it = 0; it < 21; ++it) {
        int combo = it * 4 + q;           // (di*9+dj)
        if (combo < 81) {
            float v = lds.band[wv][combo / 9][combo % 9][col];
            out[((size_t)((b * 81 + combo) * HH + h)) * WW + w0 + col] = v * scale;
        }
    }
}

extern "C" void kernel_launch(void* const* d_in, const int* in_sizes, int n_in,
                              void* d_out, int out_size, void* d_ws, size_t ws_size,
                              hipStream_t stream) {
    const float* x1 = (const float*)d_in[0];
    const float* x2 = (const float*)d_in[1];
    float* out = (float*)d_out;

    dim3 grid(WW / TW, HH / TH, NB);   // 12 x 12 x 4 = 576 blocks, 512 thr
    corr_mfma<<<grid, 512, 0, stream>>>(x1, x2, out);
}